// Round 8
// baseline (469.703 us; speedup 1.0000x reference)
//
#include <hip/hip_runtime.h>
#include <hip/hip_bf16.h>

#define NN 8192
#define FIN 256
#define FO 128
#define JCHUNK 2048             // cols per wave (4 waves cover 8192)
#define NSTEP 32                // 64-col steps per wave
#define L2E 1.4426950408889634f
#define C2  0.28853900817779268f   // 0.2 * log2(e)

typedef __bf16 bf16x8 __attribute__((ext_vector_type(8)));
typedef __bf16 bf16x2 __attribute__((ext_vector_type(2)));
typedef float  f32x4  __attribute__((ext_vector_type(4)));

// ---------------------------------------------------------------------------
// Kernel 1: h = x@W (fp32 accum), write Bpack (bf16 MFMA-B-fragment layout),
//           f_src (fp32), and G1/G2 = exp2(f_dst*log2e), exp2(f_dst*0.2*log2e).
// Bpack element (kg, nt, lane=q*16+m, t) = h[j = kg*32+q*8+t][n = nt*16+m]
// ---------------------------------------------------------------------------
__global__ __launch_bounds__(256) void k_proj(
    const float* __restrict__ x, const float* __restrict__ W,
    const float* __restrict__ a_src, const float* __restrict__ a_dst,
    __bf16* __restrict__ Bp, float* __restrict__ f_src,
    float* __restrict__ g1, float* __restrict__ g2)
{
  __shared__ float xs[16 * FIN];     // 16 KB x-tile
  __shared__ float fs[16], fd[16];
  const int tid = threadIdx.x;
  const int i0 = blockIdx.x * 16;

  const float4* xg = (const float4*)(x + (size_t)i0 * FIN);
  float4* xs4 = (float4*)xs;
  #pragma unroll
  for (int t = 0; t < 4; t++) xs4[tid + 256 * t] = xg[tid + 256 * t];
  if (tid < 16) { fs[tid] = 0.f; fd[tid] = 0.f; }
  __syncthreads();

  const int cq = tid & 31;    // column quad: cols c0..c0+3
  const int rg = tid >> 5;    // row group: rows r0, r0+1
  const int c0 = cq * 4;
  const int r0 = rg * 2;
  float acc0[4] = {0.f,0.f,0.f,0.f};
  float acc1[4] = {0.f,0.f,0.f,0.f};
  const float* xr0 = xs + r0 * FIN;
  const float* xr1 = xs + (r0 + 1) * FIN;

  for (int k = 0; k < FIN; k += 4) {
    float4 xa = *(const float4*)(xr0 + k);
    float4 xb = *(const float4*)(xr1 + k);
    #pragma unroll
    for (int kk = 0; kk < 4; kk++) {
      float4 wv = *(const float4*)(W + (size_t)(k + kk) * FO + c0);
      float xav = ((const float*)&xa)[kk];
      float xbv = ((const float*)&xb)[kk];
      acc0[0] += xav * wv.x; acc0[1] += xav * wv.y;
      acc0[2] += xav * wv.z; acc0[3] += xav * wv.w;
      acc1[0] += xbv * wv.x; acc1[1] += xbv * wv.y;
      acc1[2] += xbv * wv.z; acc1[3] += xbv * wv.w;
    }
  }

  float4 as = *(const float4*)(a_src + c0);
  float4 ad = *(const float4*)(a_dst + c0);
  float ps0 = acc0[0]*as.x + acc0[1]*as.y + acc0[2]*as.z + acc0[3]*as.w;
  float ps1 = acc1[0]*as.x + acc1[1]*as.y + acc1[2]*as.z + acc1[3]*as.w;
  float pd0 = acc0[0]*ad.x + acc0[1]*ad.y + acc0[2]*ad.z + acc0[3]*ad.w;
  float pd1 = acc1[0]*ad.x + acc1[1]*ad.y + acc1[2]*ad.z + acc1[3]*ad.w;
  atomicAdd(&fs[r0],     ps0);
  atomicAdd(&fs[r0 + 1], ps1);
  atomicAdd(&fd[r0],     pd0);
  atomicAdd(&fd[r0 + 1], pd1);

  const int j0 = i0 + r0;
  const int kg = j0 >> 5;
  const int q  = (j0 >> 3) & 3;
  const int t0 = j0 & 7;
  #pragma unroll
  for (int c = 0; c < 4; c++) {
    const int n = c0 + c;
    bf16x2 v;
    v[0] = (__bf16)acc0[c];
    v[1] = (__bf16)acc1[c];
    size_t idx = ((size_t)(kg * 8 + (n >> 4)) * 64 + q * 16 + (n & 15)) * 8 + t0;
    *(bf16x2*)(Bp + idx) = v;
  }
  __syncthreads();
  if (tid < 16) {
    float d = fd[tid];
    f_src[i0 + tid] = fs[tid];
    g1[i0 + tid] = __builtin_amdgcn_exp2f(d * L2E);
    g2[i0 + tid] = __builtin_amdgcn_exp2f(d * C2);
  }
}

// ---------------------------------------------------------------------------
// Kernel 2: streaming P@H, NO GLOBAL ATOMICS.
// 512 blocks x 256 thr (4 waves). Block owns 16 rows x all 8192 cols; wave w
// handles cols [w*2048, +2048). Separable softmax:
//   p_ij = adj ? max(F1_i*G1_j, F2_i*G2_j) : 0  (== exp(leakyrelu(s+d)))
// G1/G2 read from global (L2-resident). Depth-2 register dbuf on adj.
// Waves merge partials via LDS atomicAdd; fused divide; coalesced store.
// ---------------------------------------------------------------------------
__global__ __launch_bounds__(256, 2) void k_attn(
    const float* __restrict__ adj, const __bf16* __restrict__ Bp,
    const float* __restrict__ f_src, const float* __restrict__ g1,
    const float* __restrict__ g2, float* __restrict__ out)
{
  __shared__ float accbuf[16 * FO];   // 8 KB merge buffer (512 float4)
  __shared__ float lred[16];
  const int tid = threadIdx.x;
  const int i0 = blockIdx.x * 16;

  // zero-init ALL of accbuf: 512 float4 = 2 per thread (r7 bug: only half)
  ((float4*)accbuf)[tid]       = (float4){0.f, 0.f, 0.f, 0.f};
  ((float4*)accbuf)[tid + 256] = (float4){0.f, 0.f, 0.f, 0.f};
  if (tid < 16) lred[tid] = 0.f;

  const int w = tid >> 6;       // wave = k-split index
  const int lane = tid & 63;
  const int m = lane & 15;
  const int q = lane >> 4;
  const int jbase = w * JCHUNK;

  const float s  = f_src[i0 + m];
  const float F1 = __builtin_amdgcn_exp2f(s * L2E);
  const float F2 = __builtin_amdgcn_exp2f(s * C2);

  f32x4 acc[8];
  #pragma unroll
  for (int t = 0; t < 8; t++) acc[t] = (f32x4){0.f, 0.f, 0.f, 0.f};
  float psum = 0.f;

  const float* adjp = adj + (size_t)(i0 + m) * NN + jbase + q * 8;
  const float* g1p = g1 + jbase + q * 8;
  const float* g2p = g2 + jbase + q * 8;
  const __bf16* bb = Bp + (size_t)(jbase >> 5) * 4096 + lane * 8;

  __syncthreads();    // accbuf/lred zero-init visible before merge phase

  // depth-2 double buffer: one 64-col batch always in flight
  float4 cur0 = *(const float4*)(adjp + 0);
  float4 cur1 = *(const float4*)(adjp + 4);
  float4 cur2 = *(const float4*)(adjp + 32);
  float4 cur3 = *(const float4*)(adjp + 36);

  #pragma unroll 2
  for (int st = 0; st < NSTEP; ++st) {
    float4 nxt0, nxt1, nxt2, nxt3;
    if (st < NSTEP - 1) {
      const float* ap = adjp + (st + 1) * 64;
      nxt0 = *(const float4*)(ap + 0);
      nxt1 = *(const float4*)(ap + 4);
      nxt2 = *(const float4*)(ap + 32);
      nxt3 = *(const float4*)(ap + 36);
    }
    #pragma unroll
    for (int g = 0; g < 2; ++g) {
      const int ko = st * 64 + g * 32;
      float4 a0 = g ? cur2 : cur0;
      float4 a1 = g ? cur3 : cur1;
      float4 u0 = *(const float4*)(g1p + ko);
      float4 u1 = *(const float4*)(g1p + ko + 4);
      float4 v0 = *(const float4*)(g2p + ko);
      float4 v1 = *(const float4*)(g2p + ko + 4);
      float p0 = (a0.x > 0.f) ? fmaxf(F1 * u0.x, F2 * v0.x) : 0.f;
      float p1 = (a0.y > 0.f) ? fmaxf(F1 * u0.y, F2 * v0.y) : 0.f;
      float p2 = (a0.z > 0.f) ? fmaxf(F1 * u0.z, F2 * v0.z) : 0.f;
      float p3 = (a0.w > 0.f) ? fmaxf(F1 * u0.w, F2 * v0.w) : 0.f;
      float p4 = (a1.x > 0.f) ? fmaxf(F1 * u1.x, F2 * v1.x) : 0.f;
      float p5 = (a1.y > 0.f) ? fmaxf(F1 * u1.y, F2 * v1.y) : 0.f;
      float p6 = (a1.z > 0.f) ? fmaxf(F1 * u1.z, F2 * v1.z) : 0.f;
      float p7 = (a1.w > 0.f) ? fmaxf(F1 * u1.w, F2 * v1.w) : 0.f;
      psum += ((p0 + p1) + (p2 + p3)) + ((p4 + p5) + (p6 + p7));

      bf16x8 af;
      af[0] = (__bf16)p0; af[1] = (__bf16)p1; af[2] = (__bf16)p2; af[3] = (__bf16)p3;
      af[4] = (__bf16)p4; af[5] = (__bf16)p5; af[6] = (__bf16)p6; af[7] = (__bf16)p7;

      const __bf16* bs = bb + (size_t)(st * 2 + g) * 4096;
      #pragma unroll
      for (int nt = 0; nt < 8; nt++) {
        bf16x8 bfrag = *(const bf16x8*)(bs + nt * 512);
        acc[nt] = __builtin_amdgcn_mfma_f32_16x16x32_bf16(af, bfrag, acc[nt], 0, 0, 0);
      }
    }
    if (st < NSTEP - 1) { cur0 = nxt0; cur1 = nxt1; cur2 = nxt2; cur3 = nxt3; }
  }

  // denominator partial: rows keyed by m live in lanes {m, m+16, m+32, m+48}
  psum += __shfl_xor(psum, 16);
  psum += __shfl_xor(psum, 32);
  if (lane < 16) atomicAdd(&lred[lane], psum);

  // numerator partial merge in LDS (C/D: row=q*4+r, col=nt*16+m)
  #pragma unroll
  for (int nt = 0; nt < 8; nt++) {
    #pragma unroll
    for (int r = 0; r < 4; r++) {
      atomicAdd(&accbuf[(q * 4 + r) * FO + nt * 16 + m], acc[nt][r]);
    }
  }
  __syncthreads();

  // fused divide + coalesced store: 512 float4 = 16 rows x 128 cols
  #pragma unroll
  for (int t = 0; t < 2; t++) {
    const int idx = tid + t * 256;
    const float inv = 1.0f / lred[idx >> 5];
    float4 v = ((const float4*)accbuf)[idx];
    float4 o;
    o.x = v.x * inv; o.y = v.y * inv; o.z = v.z * inv; o.w = v.w * inv;
    ((float4*)(out + (size_t)i0 * FO))[idx] = o;
  }
}

extern "C" void kernel_launch(void* const* d_in, const int* in_sizes, int n_in,
                              void* d_out, int out_size, void* d_ws, size_t ws_size,
                              hipStream_t stream) {
  const float* x     = (const float*)d_in[0];
  const float* adj   = (const float*)d_in[1];
  const float* W     = (const float*)d_in[2];
  const float* a_src = (const float*)d_in[3];
  const float* a_dst = (const float*)d_in[4];
  float* out = (float*)d_out;

  char* ws = (char*)d_ws;
  __bf16* Bp   = (__bf16*)ws;                                  // 2 MB
  float* f_src = (float*)(ws + 2097152);                       // 32 KB
  float* g1    = (float*)(ws + 2097152 + 32768);               // 32 KB
  float* g2    = (float*)(ws + 2097152 + 65536);               // 32 KB

  hipLaunchKernelGGL(k_proj, dim3(512), dim3(256), 0, stream,
                     x, W, a_src, a_dst, Bp, f_src, g1, g2);
  hipLaunchKernelGGL(k_attn, dim3(512), dim3(256), 0, stream,
                     adj, Bp, f_src, g1, g2, out);
}